// Round 9
// baseline (1796.026 us; speedup 1.0000x reference)
//
#include <hip/hip_runtime.h>
#include <hip/hip_bf16.h>

typedef __attribute__((ext_vector_type(8))) short bf16x8;
typedef __attribute__((ext_vector_type(4))) float f32x4;
typedef __attribute__((ext_vector_type(16))) float f32x16;

#define MFMA32(a,b,c) __builtin_amdgcn_mfma_f32_32x32x16_bf16(a,b,c,0,0,0)

__device__ inline ushort f2bf(float f){
  union { float f; uint u; } v; v.f = f;
  uint r = v.u + 0x7FFFu + ((v.u >> 16) & 1u);
  return (ushort)(r >> 16);
}
__device__ inline float sigf(float x){ return 1.f/(1.f+__expf(-x)); }
__device__ inline float tanhf_(float x){ return 2.f/(1.f+__expf(-2.f*x)) - 1.f; }

__device__ inline void gload_lds16(const ushort* g, ushort* lds){
  __builtin_amdgcn_global_load_lds(
      (const __attribute__((address_space(1))) void*)g,
      (__attribute__((address_space(3))) void*)lds, 16, 0, 0);
}

// ---------------- weight fp32 -> bf16 conversion ----------------
__global__ void convert_weights(const float* __restrict__ s0, const float* __restrict__ s1,
                                const float* __restrict__ s2, const float* __restrict__ s3,
                                ushort* __restrict__ dst){
  size_t i4 = ((size_t)blockIdx.x*256 + threadIdx.x)*4;
  int tsel = (int)(i4 >> 21);
  const float* s = (tsel & 2) ? ((tsel & 1) ? s3 : s2) : ((tsel & 1) ? s1 : s0);
  size_t off = i4 & 2097151u;
  float4 v = *(const float4*)&s[off];
  ushort4 o; o.x=f2bf(v.x); o.y=f2bf(v.y); o.z=f2bf(v.z); o.w=f2bf(v.w);
  *(ushort4*)&dst[i4] = o;
}

// ---------------- embed ----------------
__global__ void embed_kernel(const float* __restrict__ obsVel, const float* __restrict__ mean,
                             const float* __restrict__ stdv, const float* __restrict__ encW,
                             const float* __restrict__ encb, ushort* __restrict__ embed){
  int idx = blockIdx.x*256 + threadIdx.x;   // < 32768*64
  int row = idx >> 6, c8 = (idx & 63) * 8;
  float x0 = (obsVel[row*2+0] - mean[0]) / stdv[0];
  float x1 = (obsVel[row*2+1] - mean[1]) / stdv[1];
  ushort o[8];
  #pragma unroll
  for (int j=0;j<8;j++){
    int col = c8 + j;
    o[j] = f2bf(x0*encW[col] + x1*encW[512+col] + encb[col]);
  }
  *(uint4*)&embed[(size_t)row*512 + c8] = *(const uint4*)o;
}

// ---------------- fused LSTM cell step ----------------
// 256 thr, 2x2 waves. Wave tile 64 rows x 64 gcols (2 gates x 32 cols).
// Block tile 128 rows x (4 gates x 32 cols). BK=64, 32x32x16 MFMA.
// A: direct global->reg (r6-proven), double-buffered in named reg sets.
// B: LDS only, 2 bufs x 16 KB = 32 KB -> 2 blocks/CU. Swizzle: logical row r
// (128 B) at LDS row r, slot(r,c) = c ^ (r&7) (0-conflict family, r4/r8).
// Epilogue: gates live in different wc-waves -> one-time 32 KB LDS exchange
// (plane = [quad][lane*16B], conflict-free), reusing the B buffers.
#define NKT_SEG 8   // K=512 per segment / BK=64

__global__ __launch_bounds__(256, 2) void lstm_cell_kernel(
    const ushort* __restrict__ A0, int lda0,
    const ushort* __restrict__ A1, int lda1,
    const ushort* __restrict__ B0,
    const ushort* __restrict__ B1,
    const float*  __restrict__ bias,
    float* __restrict__ C,
    ushort* __restrict__ H0, int ldh0,
    ushort* __restrict__ H1, int ldh1,
    int nSeg, int czero)
{
  __shared__ ushort bL[2][8192];   // 128 logical rows x 128 B, swizzled
  const int tid = threadIdx.x;
  const int w = tid >> 6, lane = tid & 63;
  const int wr = w >> 1, wc = w & 1;
  const int bm = blockIdx.y * 128;
  const int bn = blockIdx.x * 32;            // col base within each gate

  f32x16 acc[2][2];   // [mf][nf]; nf -> gate 2*wc+nf
  #pragma unroll
  for (int m=0;m<2;m++)
    #pragma unroll
    for (int n=0;n<2;n++) acc[m][n] = (f32x16)0.f;

  // ---- B staging: 4 chunks/thread/tile; inverse swizzle ----
  size_t bsrc[4]; int ldsO[4];
  #pragma unroll
  for (int p=0;p<4;p++){
    int i = p*256 + tid;
    int r = i>>3, s = i&7, c = s ^ (r&7);
    bsrc[p] = (size_t)((r>>5)*512 + bn + (r&31))*512 + c*8;
    ldsO[p] = (p*256 + (tid & ~63)) * 8;   // wave-uniform base (ushort units)
  }

  // ---- B frag read offsets (ushort units): nf in {0,1}, ks in {0..3} ----
  int bOff[2][4];
  #pragma unroll
  for (int nf=0;nf<2;nf++){
    int r = (2*wc+nf)*32 + (lane&31);
    #pragma unroll
    for (int ks=0;ks<4;ks++){
      int slot = (ks*2 + (lane>>5)) ^ (r&7);
      bOff[nf][ks] = r*64 + slot*8;
    }
  }

  // ---- A direct-load geometry ----
  const int ar0 = bm + wr*64 + (lane&31);   // mf=0
  const int ar1 = ar0 + 32;                 // mf=1
  const int ak  = (lane>>5)*8;

  #define STAGE_B(bi, kt) do { \
    const ushort* Bseg = ((kt) < NKT_SEG) ? B0 : B1; \
    const int k0_ = ((kt) & (NKT_SEG-1)) << 6; \
    _Pragma("unroll") \
    for (int p=0;p<4;p++) \
      gload_lds16(Bseg + bsrc[p] + k0_, &bL[bi][ldsO[p]]); \
  } while(0)

  #define LOAD_A(AF, kt) do { \
    const ushort* Aseg = ((kt) < NKT_SEG) ? A0 : A1; \
    const int lda_     = ((kt) < NKT_SEG) ? lda0 : lda1; \
    const int k0_ = (((kt) & (NKT_SEG-1)) << 6) + ak; \
    const ushort* p0_ = Aseg + (size_t)ar0*lda_ + k0_; \
    const ushort* p1_ = Aseg + (size_t)ar1*lda_ + k0_; \
    _Pragma("unroll") \
    for (int ks=0;ks<4;ks++){ \
      AF[0][ks] = *(const bf16x8*)(p0_ + ks*16); \
      AF[1][ks] = *(const bf16x8*)(p1_ + ks*16); \
    } \
  } while(0)

  #define COMPUTE(bi, AF) do { \
    _Pragma("unroll") \
    for (int ks=0;ks<4;ks++){ \
      bf16x8 b0_ = *(const bf16x8*)&bL[bi][bOff[0][ks]]; \
      bf16x8 b1_ = *(const bf16x8*)&bL[bi][bOff[1][ks]]; \
      __builtin_amdgcn_s_setprio(1); \
      acc[0][0] = MFMA32(AF[0][ks], b0_, acc[0][0]); \
      acc[0][1] = MFMA32(AF[0][ks], b1_, acc[0][1]); \
      acc[1][0] = MFMA32(AF[1][ks], b0_, acc[1][0]); \
      acc[1][1] = MFMA32(AF[1][ks], b1_, acc[1][1]); \
      __builtin_amdgcn_s_setprio(0); \
    } \
  } while(0)

  const int nkt = nSeg * NKT_SEG;   // 8 or 16 (even)
  bf16x8 aA[2][4], aB[2][4];

  STAGE_B(0, 0);
  LOAD_A(aA, 0);
  __syncthreads();

  for (int kt=0; kt<nkt; kt+=2){
    STAGE_B(1, kt+1);  LOAD_A(aB, kt+1);
    COMPUTE(0, aA);
    __syncthreads();
    if (kt+2 < nkt){ STAGE_B(0, kt+2); LOAD_A(aA, kt+2); }
    COMPUTE(1, aB);
    __syncthreads();
  }
  #undef STAGE_B
  #undef LOAD_A
  #undef COMPUTE

  // ---- gate exchange: wave (wr,wc) handles rows mf=wc; needs other pair ----
  float* xch = (float*)bL;
  // plane(wr,mf,nf): 4 KB each; layout: quad q at plane + q*256 floats + lane*4
  #define XWRITE(V, PW, PM, PN) do { \
    float* pl_ = xch + (((((PW)*2+(PM))*2)+(PN))<<10); \
    _Pragma("unroll") \
    for (int q=0;q<4;q++){ \
      f32x4 v_; v_[0]=(V)[q*4]; v_[1]=(V)[q*4+1]; v_[2]=(V)[q*4+2]; v_[3]=(V)[q*4+3]; \
      *(f32x4*)(pl_ + q*256 + lane*4) = v_; \
    } \
  } while(0)
  #define XREAD(V, PW, PM, PN) do { \
    float* pl_ = xch + (((((PW)*2+(PM))*2)+(PN))<<10); \
    _Pragma("unroll") \
    for (int q=0;q<4;q++){ \
      f32x4 v_ = *(f32x4*)(pl_ + q*256 + lane*4); \
      (V)[q*4]=v_[0]; (V)[q*4+1]=v_[1]; (V)[q*4+2]=v_[2]; (V)[q*4+3]=v_[3]; \
    } \
  } while(0)

  if (wc == 0){ XWRITE(acc[1][0], wr, 1, 0); XWRITE(acc[1][1], wr, 1, 1); }
  else        { XWRITE(acc[0][0], wr, 0, 0); XWRITE(acc[0][1], wr, 0, 1); }
  __syncthreads();
  f32x16 fA, fB;
  XREAD(fA, wr, wc, 0);
  XREAD(fB, wr, wc, 1);
  #undef XWRITE
  #undef XREAD

  f32x16 gI, gF, gG, gO;
  if (wc == 0){ gI = acc[0][0]; gF = acc[0][1]; gG = fA; gO = fB; }
  else        { gI = fA;        gF = fB;        gG = acc[1][0]; gO = acc[1][1]; }

  // ---- epilogue: bias + gates, c update, h writes ----
  const int colc = bn + (lane&31);
  const float b_i = bias[colc];
  const float b_f = bias[512+colc];
  const float b_g = bias[1024+colc];
  const float b_o = bias[1536+colc];
  const int rbase = bm + wr*64 + wc*32 + ((lane>>5)<<2);
  #pragma unroll
  for (int reg=0;reg<16;reg++){
    const int row = rbase + (reg&3) + ((reg>>2)<<3);
    float gi = gI[reg] + b_i;
    float gf = gF[reg] + b_f;
    float gg = gG[reg] + b_g;
    float go = gO[reg] + b_o;
    size_t cidx = (size_t)row*512 + colc;
    float cv = czero ? 0.f : C[cidx];
    float cn = sigf(gf)*cv + sigf(gi)*tanhf_(gg);
    float hv = sigf(go)*tanhf_(cn);
    C[cidx] = cn;
    ushort hb = f2bf(hv);
    H0[(size_t)row*ldh0 + colc] = hb;
    if (H1) H1[(size_t)row*ldh1 + colc] = hb;
  }
}

// ---------------- projection + cumsum ----------------
__global__ void final_kernel(const ushort* __restrict__ pred, const float* __restrict__ decW,
                             const float* __restrict__ decb, const float* __restrict__ mean,
                             const float* __restrict__ stdv, const float* __restrict__ obs,
                             float* __restrict__ out){
  int w = threadIdx.x >> 6, lane = threadIdx.x & 63;
  int b = blockIdx.x*4 + w;
  float w0[8], w1[8];
  #pragma unroll
  for (int j=0;j<8;j++){
    int k = lane*8 + j;
    w0[j] = decW[k*2+0];
    w1[j] = decW[k*2+1];
  }
  float cum0 = 0.f, cum1 = 0.f;
  float m0 = mean[0], m1 = mean[1], sv0 = stdv[0], sv1 = stdv[1];
  float o0 = obs[(b*8+7)*2+0], o1 = obs[(b*8+7)*2+1];
  float db0 = decb[0], db1 = decb[1];
  for (int t=0;t<12;t++){
    const uint4 q = *(const uint4*)&pred[((size_t)b*12+t)*512 + lane*8];
    uint u[4] = {q.x,q.y,q.z,q.w};
    float s0=0.f, s1=0.f;
    #pragma unroll
    for (int p=0;p<4;p++){
      float lo = __uint_as_float(u[p]<<16);
      float hi = __uint_as_float(u[p]&0xffff0000u);
      s0 += lo*w0[2*p] + hi*w0[2*p+1];
      s1 += lo*w1[2*p] + hi*w1[2*p+1];
    }
    #pragma unroll
    for (int off=32; off>0; off>>=1){ s0 += __shfl_down(s0, off); s1 += __shfl_down(s1, off); }
    if (lane==0){
      cum0 += (s0+db0)*sv0 + m0;
      cum1 += (s1+db1)*sv1 + m1;
      out[((size_t)b*12+t)*2+0] = cum0 + o0;
      out[((size_t)b*12+t)*2+1] = cum1 + o1;
    }
  }
}

extern "C" void kernel_launch(void* const* d_in, const int* in_sizes, int n_in,
                              void* d_out, int out_size, void* d_ws, size_t ws_size,
                              hipStream_t stream) {
  const float* obs      = (const float*)d_in[0];
  const float* obsVel   = (const float*)d_in[1];
  const float* mean     = (const float*)d_in[2];
  const float* stdv     = (const float*)d_in[3];
  const float* encW     = (const float*)d_in[5];
  const float* encb     = (const float*)d_in[6];
  const float* decW     = (const float*)d_in[7];
  const float* decb     = (const float*)d_in[8];
  const float* lstm_Wih = (const float*)d_in[9];
  const float* lstm_Whh = (const float*)d_in[10];
  const float* lstm_b   = (const float*)d_in[11];
  const float* cell_Wih = (const float*)d_in[12];
  const float* cell_Whh = (const float*)d_in[13];
  const float* cell_b   = (const float*)d_in[14];

  char* ws = (char*)d_ws;
  ushort* wbf   = (ushort*)ws;                       // 16 MB
  ushort* embed = (ushort*)(ws + (16ull<<20));       // 32 MB
  ushort* h0[2] = {(ushort*)(ws + (48ull<<20)), (ushort*)(ws + (52ull<<20))};
  ushort* h1[2] = {(ushort*)(ws + (56ull<<20)), (ushort*)(ws + (60ull<<20))};
  float*  c0    = (float*)(ws + (64ull<<20));
  float*  c1    = (float*)(ws + (72ull<<20));
  ushort* pred  = (ushort*)(ws + (80ull<<20));       // 48 MB

  ushort* w_lstm_ih = wbf;
  ushort* w_lstm_hh = wbf + 2097152;
  ushort* w_cell_ih = wbf + 4194304;
  ushort* w_cell_hh = wbf + 6291456;

  convert_weights<<<8192, 256, 0, stream>>>(lstm_Wih, lstm_Whh, cell_Wih, cell_Whh, wbf);
  embed_kernel<<<8192, 256, 0, stream>>>(obsVel, mean, stdv, encW, encb, embed);

  dim3 grid(16, 32);
  int cur0 = 0, cur1 = 0;
  for (int t=0;t<8;t++){
    int ns = (t==0) ? 1 : 2;
    int cz = (t==0) ? 1 : 0;
    lstm_cell_kernel<<<grid, 256, 0, stream>>>(embed + t*512, 4096, h0[cur0], 512,
        w_lstm_ih, w_lstm_hh, lstm_b, c0, h0[cur0^1], 512, (ushort*)nullptr, 0, ns, cz);
    lstm_cell_kernel<<<grid, 256, 0, stream>>>(h0[cur0^1], 512, h1[cur1], 512,
        w_lstm_ih + 1048576, w_lstm_hh + 1048576, lstm_b + 2048, c1, h1[cur1^1], 512,
        (t==7) ? pred : (ushort*)nullptr, 6144, ns, cz);
    cur0 ^= 1; cur1 ^= 1;
  }
  for (int s=1;s<12;s++){
    lstm_cell_kernel<<<grid, 256, 0, stream>>>(pred + (s-1)*512, 6144, h0[cur0], 512,
        w_cell_ih, w_cell_hh, cell_b, c0, h0[cur0^1], 512, (ushort*)nullptr, 0, 2, 0);
    lstm_cell_kernel<<<grid, 256, 0, stream>>>(h0[cur0^1], 512, h1[cur1], 512,
        w_cell_ih + 1048576, w_cell_hh + 1048576, cell_b + 2048, c1, h1[cur1^1], 512,
        pred + s*512, 6144, 2, 0);
    cur0 ^= 1; cur1 ^= 1;
  }
  final_kernel<<<1024, 256, 0, stream>>>(pred, decW, decb, mean, stdv, obs, (float*)d_out);
}

// Round 10
// 1110.954 us; speedup vs baseline: 1.6167x; 1.6167x over previous
//
#include <hip/hip_runtime.h>
#include <hip/hip_bf16.h>

typedef __attribute__((ext_vector_type(8))) short bf16x8;
typedef __attribute__((ext_vector_type(4))) float f32x4;

#define MFMA16(a,b,c) __builtin_amdgcn_mfma_f32_16x16x32_bf16(a,b,c,0,0,0)

__device__ inline ushort f2bf(float f){
  union { float f; uint u; } v; v.f = f;
  uint r = v.u + 0x7FFFu + ((v.u >> 16) & 1u);
  return (ushort)(r >> 16);
}
__device__ inline float sigf(float x){ return 1.f/(1.f+__expf(-x)); }
__device__ inline float tanhf_(float x){ return 2.f/(1.f+__expf(-2.f*x)) - 1.f; }

__device__ inline void gload_lds16(const ushort* g, ushort* lds){
  __builtin_amdgcn_global_load_lds(
      (const __attribute__((address_space(1))) void*)g,
      (__attribute__((address_space(3))) void*)lds, 16, 0, 0);
}

// ---------------- weight fp32 -> bf16 conversion ----------------
__global__ void convert_weights(const float* __restrict__ s0, const float* __restrict__ s1,
                                const float* __restrict__ s2, const float* __restrict__ s3,
                                ushort* __restrict__ dst){
  size_t i4 = ((size_t)blockIdx.x*256 + threadIdx.x)*4;
  int tsel = (int)(i4 >> 21);
  const float* s = (tsel & 2) ? ((tsel & 1) ? s3 : s2) : ((tsel & 1) ? s1 : s0);
  size_t off = i4 & 2097151u;
  float4 v = *(const float4*)&s[off];
  ushort4 o; o.x=f2bf(v.x); o.y=f2bf(v.y); o.z=f2bf(v.z); o.w=f2bf(v.w);
  *(ushort4*)&dst[i4] = o;
}

// ---------------- embed ----------------
__global__ void embed_kernel(const float* __restrict__ obsVel, const float* __restrict__ mean,
                             const float* __restrict__ stdv, const float* __restrict__ encW,
                             const float* __restrict__ encb, ushort* __restrict__ embed){
  int idx = blockIdx.x*256 + threadIdx.x;   // < 32768*64
  int row = idx >> 6, c8 = (idx & 63) * 8;
  float x0 = (obsVel[row*2+0] - mean[0]) / stdv[0];
  float x1 = (obsVel[row*2+1] - mean[1]) / stdv[1];
  ushort o[8];
  #pragma unroll
  for (int j=0;j<8;j++){
    int col = c8 + j;
    o[j] = f2bf(x0*encW[col] + x1*encW[512+col] + encb[col]);
  }
  *(uint4*)&embed[(size_t)row*512 + c8] = *(const uint4*)o;
}

// ---------------- fused LSTM cell step ----------------
// r6 geometry (best: 1122us) + T3/T4 counted-vmcnt pipeline:
// 256 thr = 4 waves M-stacked (wave: 32 rows x 128 gcols). Block 128x128 of g.
// BK=64. A: direct global->reg, 1-iter prefetch (named sets). B: LDS,
// 3 bufs x 16 KB = 48 KB, depth-2 staging. Per iter: STAGE(k+2), LOAD_A(k+1),
// COMPUTE(k), then vmcnt(8) (= A(k+1)+stage(k+2) in flight; forces only the
// one-iter-old stage(k+1)) + raw s_barrier — NO vmcnt(0) drain of fresh loads
// (r6's __syncthreads pathology). C/bias prefetched before loop (oldest VMEM).
#define NKT_SEG 8   // K=512 per segment / BK=64

__global__ __launch_bounds__(256, 2) void lstm_cell_kernel(
    const ushort* __restrict__ A0, int lda0,
    const ushort* __restrict__ A1, int lda1,
    const ushort* __restrict__ B0,
    const ushort* __restrict__ B1,
    const float*  __restrict__ bias,
    float* __restrict__ C,
    ushort* __restrict__ H0, int ldh0,
    ushort* __restrict__ H1, int ldh1,
    int nSeg, int czero)
{
  __shared__ ushort bL[3][8192];   // 128 g-rows x 64 k bf16 per buf, swizzled
  const int tid = threadIdx.x;
  const int w = tid >> 6, lane = tid & 63;
  const int bm = blockIdx.y * 128;
  const int bn = blockIdx.x * 32;            // gate-local col base

  // ---- epilogue operand prefetch (oldest VMEM; latency hidden by GEMM) ----
  const int r0 = bm + w*32 + ((lane>>4)<<2);
  float br[2][4], creg[2][2][4];
  #pragma unroll
  for (int cc=0;cc<2;cc++){
    const int ccol = bn + cc*16 + (lane&15);
    br[cc][0] = bias[ccol];
    br[cc][1] = bias[512+ccol];
    br[cc][2] = bias[1024+ccol];
    br[cc][3] = bias[1536+ccol];
  }
  if (czero){
    #pragma unroll
    for (int cc=0;cc<2;cc++)
      #pragma unroll
      for (int m=0;m<2;m++)
        #pragma unroll
        for (int reg=0;reg<4;reg++) creg[cc][m][reg] = 0.f;
  } else {
    #pragma unroll
    for (int cc=0;cc<2;cc++){
      const int ccol = bn + cc*16 + (lane&15);
      #pragma unroll
      for (int m=0;m<2;m++)
        #pragma unroll
        for (int reg=0;reg<4;reg++)
          creg[cc][m][reg] = C[(size_t)(r0 + m*16 + reg)*512 + ccol];
    }
  }

  f32x4 acc[2][8];
  #pragma unroll
  for (int m=0;m<2;m++)
    #pragma unroll
    for (int n=0;n<8;n++) acc[m][n] = (f32x4)0.f;

  // ---- B staging: 4 chunks/thread/tile; inverse swizzle (r6, 0-conflict) ----
  int boff[4], ldsO[4];
  #pragma unroll
  for (int p=0;p<4;p++){
    int i = p*256 + tid;
    int r = i>>3, s = i&7, ch = s ^ (r&7);
    boff[p] = (((r>>5)<<9) + bn + (r&31))*512 + ch*8;   // elem offset in B seg
    ldsO[p] = (p*256 + (tid & ~63)) * 8;                // wave-uniform base
  }

  // ---- A direct-load geometry (wave-private rows) ----
  const int arow0 = bm + w*32 + (lane&15);
  const int arow1 = arow0 + 16;
  const int ca = (lane>>4)*8;

  // ---- B frag read offsets (ushort units); kk=1 -> ^32 ----
  int bOff[8];
  #pragma unroll
  for (int n=0;n<8;n++){
    int row = (n>>1)*32 + (n&1)*16 + (lane&15);
    int slot = (lane>>4) ^ (row&7);
    bOff[n] = row*64 + slot*8;
  }

  #define STAGE_B(bi, kt) do { \
    const ushort* Bseg = ((kt) < NKT_SEG) ? B0 : B1; \
    const int k0_ = ((kt) & (NKT_SEG-1)) << 6; \
    _Pragma("unroll") \
    for (int p=0;p<4;p++) \
      gload_lds16(Bseg + boff[p] + k0_, &bL[bi][ldsO[p]]); \
  } while(0)

  #define LOAD_A(AF, kt) do { \
    const ushort* Aseg = ((kt) < NKT_SEG) ? A0 : A1; \
    const int lda_     = ((kt) < NKT_SEG) ? lda0 : lda1; \
    const int k0_ = (((kt) & (NKT_SEG-1)) << 6) + ca; \
    const ushort* pa0_ = Aseg + (size_t)arow0*lda_ + k0_; \
    const ushort* pa1_ = Aseg + (size_t)arow1*lda_ + k0_; \
    AF[0][0] = *(const bf16x8*)pa0_;  AF[0][1] = *(const bf16x8*)(pa0_+32); \
    AF[1][0] = *(const bf16x8*)pa1_;  AF[1][1] = *(const bf16x8*)(pa1_+32); \
  } while(0)

  #define COMPUTE(bi, AF) do { \
    bf16x8 bfr[8]; \
    _Pragma("unroll") \
    for (int n=0;n<8;n++) bfr[n] = *(const bf16x8*)&bL[bi][bOff[n]]; \
    __builtin_amdgcn_s_setprio(1); \
    _Pragma("unroll") \
    for (int m=0;m<2;m++) \
      _Pragma("unroll") \
      for (int n=0;n<8;n++) acc[m][n] = MFMA16(AF[m][0], bfr[n], acc[m][n]); \
    __builtin_amdgcn_s_setprio(0); \
    _Pragma("unroll") \
    for (int n=0;n<8;n++) bfr[n] = *(const bf16x8*)&bL[bi][bOff[n]^32]; \
    __builtin_amdgcn_s_setprio(1); \
    _Pragma("unroll") \
    for (int m=0;m<2;m++) \
      _Pragma("unroll") \
      for (int n=0;n<8;n++) acc[m][n] = MFMA16(AF[m][1], bfr[n], acc[m][n]); \
    __builtin_amdgcn_s_setprio(0); \
  } while(0)

  #define SYNC_CNT(N) do { \
    __builtin_amdgcn_sched_barrier(0); \
    asm volatile("s_waitcnt vmcnt(" #N ")" ::: "memory"); \
    __builtin_amdgcn_s_barrier(); \
    __builtin_amdgcn_sched_barrier(0); \
  } while(0)

  const int nkt = nSeg * NKT_SEG;   // 8 or 16 (even)
  bf16x8 aA[2][2], aB[2][2];
  int b0 = 0, b1 = 1, b2 = 2;

  // prologue: stage 2 tiles, load A(0); wait only stage(0) (8 newer in flight)
  STAGE_B(0, 0);
  STAGE_B(1, 1);
  LOAD_A(aA, 0);
  SYNC_CNT(8);

  for (int kt = 0; kt < nkt-2; kt += 2){
    // iter kt: stage kt+2, load A(kt+1), compute kt
    STAGE_B(b2, kt+2);
    LOAD_A(aB, kt+1);
    COMPUTE(b0, aA);
    SYNC_CNT(8);
    { int t_ = b0; b0 = b1; b1 = b2; b2 = t_; }
    // iter kt+1
    STAGE_B(b2, kt+3 < nkt ? kt+3 : kt+2);   // kt+3==nkt only when kt==nkt-3 (never: kt even, nkt even)
    LOAD_A(aA, kt+2);
    COMPUTE(b0, aB);
    SYNC_CNT(8);
    { int t_ = b0; b0 = b1; b1 = b2; b2 = t_; }
  }
  // tail: kt = nkt-2 (aA current, buf b0), then nkt-1 (aB, buf b1)
  LOAD_A(aB, nkt-1);
  COMPUTE(b0, aA);
  SYNC_CNT(4);
  COMPUTE(b1, aB);

  #undef STAGE_B
  #undef LOAD_A
  #undef COMPUTE
  #undef SYNC_CNT

  // ---- epilogue: bias + gates, c update, h writes ----
  #pragma unroll
  for (int cc=0;cc<2;cc++){
    const int ccol = bn + cc*16 + (lane&15);
    const float bi = br[cc][0], bff = br[cc][1], bg = br[cc][2], bo = br[cc][3];
    #pragma unroll
    for (int m=0;m<2;m++){
      #pragma unroll
      for (int reg=0;reg<4;reg++){
        const int row = r0 + m*16 + reg;
        float gi = acc[m][0+cc][reg] + bi;
        float gf = acc[m][2+cc][reg] + bff;
        float gg = acc[m][4+cc][reg] + bg;
        float go = acc[m][6+cc][reg] + bo;
        float cn = sigf(gf)*creg[cc][m][reg] + sigf(gi)*tanhf_(gg);
        float hv = sigf(go)*tanhf_(cn);
        C[(size_t)row*512 + ccol] = cn;
        ushort hb = f2bf(hv);
        H0[(size_t)row*ldh0 + ccol] = hb;
        if (H1) H1[(size_t)row*ldh1 + ccol] = hb;
      }
    }
  }
}

// ---------------- projection + cumsum ----------------
__global__ void final_kernel(const ushort* __restrict__ pred, const float* __restrict__ decW,
                             const float* __restrict__ decb, const float* __restrict__ mean,
                             const float* __restrict__ stdv, const float* __restrict__ obs,
                             float* __restrict__ out){
  int w = threadIdx.x >> 6, lane = threadIdx.x & 63;
  int b = blockIdx.x*4 + w;
  float w0[8], w1[8];
  #pragma unroll
  for (int j=0;j<8;j++){
    int k = lane*8 + j;
    w0[j] = decW[k*2+0];
    w1[j] = decW[k*2+1];
  }
  float cum0 = 0.f, cum1 = 0.f;
  float m0 = mean[0], m1 = mean[1], sv0 = stdv[0], sv1 = stdv[1];
  float o0 = obs[(b*8+7)*2+0], o1 = obs[(b*8+7)*2+1];
  float db0 = decb[0], db1 = decb[1];
  for (int t=0;t<12;t++){
    const uint4 q = *(const uint4*)&pred[((size_t)b*12+t)*512 + lane*8];
    uint u[4] = {q.x,q.y,q.z,q.w};
    float s0=0.f, s1=0.f;
    #pragma unroll
    for (int p=0;p<4;p++){
      float lo = __uint_as_float(u[p]<<16);
      float hi = __uint_as_float(u[p]&0xffff0000u);
      s0 += lo*w0[2*p] + hi*w0[2*p+1];
      s1 += lo*w1[2*p] + hi*w1[2*p+1];
    }
    #pragma unroll
    for (int off=32; off>0; off>>=1){ s0 += __shfl_down(s0, off); s1 += __shfl_down(s1, off); }
    if (lane==0){
      cum0 += (s0+db0)*sv0 + m0;
      cum1 += (s1+db1)*sv1 + m1;
      out[((size_t)b*12+t)*2+0] = cum0 + o0;
      out[((size_t)b*12+t)*2+1] = cum1 + o1;
    }
  }
}

extern "C" void kernel_launch(void* const* d_in, const int* in_sizes, int n_in,
                              void* d_out, int out_size, void* d_ws, size_t ws_size,
                              hipStream_t stream) {
  const float* obs      = (const float*)d_in[0];
  const float* obsVel   = (const float*)d_in[1];
  const float* mean     = (const float*)d_in[2];
  const float* stdv     = (const float*)d_in[3];
  const float* encW     = (const float*)d_in[5];
  const float* encb     = (const float*)d_in[6];
  const float* decW     = (const float*)d_in[7];
  const float* decb     = (const float*)d_in[8];
  const float* lstm_Wih = (const float*)d_in[9];
  const float* lstm_Whh = (const float*)d_in[10];
  const float* lstm_b   = (const float*)d_in[11];
  const float* cell_Wih = (const float*)d_in[12];
  const float* cell_Whh = (const float*)d_in[13];
  const float* cell_b   = (const float*)d_in[14];

  char* ws = (char*)d_ws;
  ushort* wbf   = (ushort*)ws;                       // 16 MB
  ushort* embed = (ushort*)(ws + (16ull<<20));       // 32 MB
  ushort* h0[2] = {(ushort*)(ws + (48ull<<20)), (ushort*)(ws + (52ull<<20))};
  ushort* h1[2] = {(ushort*)(ws + (56ull<<20)), (ushort*)(ws + (60ull<<20))};
  float*  c0    = (float*)(ws + (64ull<<20));
  float*  c1    = (float*)(ws + (72ull<<20));
  ushort* pred  = (ushort*)(ws + (80ull<<20));       // 48 MB

  ushort* w_lstm_ih = wbf;
  ushort* w_lstm_hh = wbf + 2097152;
  ushort* w_cell_ih = wbf + 4194304;
  ushort* w_cell_hh = wbf + 6291456;

  convert_weights<<<8192, 256, 0, stream>>>(lstm_Wih, lstm_Whh, cell_Wih, cell_Whh, wbf);
  embed_kernel<<<8192, 256, 0, stream>>>(obsVel, mean, stdv, encW, encb, embed);

  dim3 grid(16, 32);
  int cur0 = 0, cur1 = 0;
  for (int t=0;t<8;t++){
    int ns = (t==0) ? 1 : 2;
    int cz = (t==0) ? 1 : 0;
    lstm_cell_kernel<<<grid, 256, 0, stream>>>(embed + t*512, 4096, h0[cur0], 512,
        w_lstm_ih, w_lstm_hh, lstm_b, c0, h0[cur0^1], 512, (ushort*)nullptr, 0, ns, cz);
    lstm_cell_kernel<<<grid, 256, 0, stream>>>(h0[cur0^1], 512, h1[cur1], 512,
        w_lstm_ih + 1048576, w_lstm_hh + 1048576, lstm_b + 2048, c1, h1[cur1^1], 512,
        (t==7) ? pred : (ushort*)nullptr, 6144, ns, cz);
    cur0 ^= 1; cur1 ^= 1;
  }
  for (int s=1;s<12;s++){
    lstm_cell_kernel<<<grid, 256, 0, stream>>>(pred + (s-1)*512, 6144, h0[cur0], 512,
        w_cell_ih, w_cell_hh, cell_b, c0, h0[cur0^1], 512, (ushort*)nullptr, 0, 2, 0);
    lstm_cell_kernel<<<grid, 256, 0, stream>>>(h0[cur0^1], 512, h1[cur1], 512,
        w_cell_ih + 1048576, w_cell_hh + 1048576, cell_b + 2048, c1, h1[cur1^1], 512,
        pred + s*512, 6144, 2, 0);
    cur0 ^= 1; cur1 ^= 1;
  }
  final_kernel<<<1024, 256, 0, stream>>>(pred, decW, decb, mean, stdv, obs, (float*)d_out);
}